// Round 11
// baseline (3450.416 us; speedup 1.0000x reference)
//
#include <hip/hip_runtime.h>

#define NB 32
#define NP 65536
#define NS 1024
#define NT 1024
#define BPB 8                 // blocks per batch
#define CHUNK (NP / BPB)      // 8192 points per block
#define PPT (CHUNK / NT)      // 8 points per thread
#define FAST_ATT 24           // bounded sc0 poll attempts
#define DEMOTE_AFTER 2        // consecutive fast-timeouts -> lane safe-only

typedef unsigned long long u64;
typedef unsigned int u32;
typedef int int4v __attribute__((ext_vector_type(4)));

// ---------------- R11: R7 block mapping (CONSECUTIVE bids per batch) --------
// R10 evidence: XCD assignment is chunked (bid/32), not round-robin. R7's
// b=bid>>3 puts a batch's 8 blocks on consecutive bids -> one XCD chunk
// (8b mod 32 in {0,8,16,24}, never straddles). Fast sc0 polls then hit the
// SAME XCD's L2. Everything else identical to R10 (completed, absmax 0):
// write-once tag-validated 32B slots, dual-visibility store, bounded fast
// poll with per-lane demotion to the R7-proven sc0sc1 loop.
// CONTROL FLOW RULE (R8/R9 deadlock): writer store is a separate, loop-free
// `if (lane==0)` that completes before any poll loop starts.
__global__ __launch_bounds__(NT) void fps_v11(const float* __restrict__ pts,
                                              float* __restrict__ out,
                                              u32* __restrict__ slots) {
#pragma clang fp contract(off)
    const int bid = blockIdx.x;
    const int b = bid >> 3;           // batch: blocks 8b..8b+7 (one XCD chunk)
    const int j = bid & 7;            // sub-block within batch
    const int t = threadIdx.x;
    const int wave = t >> 6;
    const int lane = t & 63;
    const int base = j * CHUNK;
    const float* __restrict__ pb = pts + (size_t)b * NP * 3;
    float* __restrict__ out_idx = out + (size_t)b * NS;
    float* __restrict__ out_pts = out + (size_t)NB * NS + (size_t)b * NS * 3;
    u32* __restrict__ slot_b = slots + (size_t)b * NS * BPB * 8;  // u32 words

    __shared__ float P[CHUNK * 3];    // 96 KB packed points
    __shared__ u64 cand[NT / 64];
    __shared__ int sel_hist[NS];
    __shared__ float qsh[3];

    // stage chunk into LDS, coalesced float4
    {
        const float4* __restrict__ src4 = (const float4*)(pb + (size_t)base * 3);
        float4* dst4 = (float4*)P;
#pragma unroll
        for (int k = 0; k < (CHUNK * 3 / 4) / NT; ++k) dst4[t + k * NT] = src4[t + k * NT];
    }
    if (t == 0) {
        sel_hist[0] = 0;
        if (j == 0) out_idx[0] = 0.0f;
        qsh[0] = pb[0]; qsh[1] = pb[1]; qsh[2] = pb[2];   // first sel = point 0
    }
    __syncthreads();

    // points -> registers, CONSECUTIVE per-thread range [t*8, t*8+8):
    // lowest lane then == lowest global idx (exact ballot tie-break)
    float px[PPT], py[PPT], pz[PPT], md[PPT];
#pragma unroll
    for (int i = 0; i < PPT; ++i) {
        const int li = t * PPT + i;
        px[i] = P[li * 3 + 0];
        py[i] = P[li * 3 + 1];
        pz[i] = P[li * 3 + 2];
        md[i] = 1e10f;
    }
    float qx = qsh[0], qy = qsh[1], qz = qsh[2];

    int usefast = 1, fastfail = 0;    // per-lane poll mode (wave0 lanes 0-7)

    for (int s = 1; s < NS; ++s) {
        float bv = -1.0f;
        int bi = 0;
#pragma unroll
        for (int i = 0; i < PPT; ++i) {
            float dx = px[i] - qx;
            float dy = py[i] - qy;
            float dz = pz[i] - qz;
            float d = (dx * dx + dy * dy) + dz * dz;   // match np reduce order
            float nmd = fminf(md[i], d);
            md[i] = nmd;
            if (nmd > bv) { bv = nmd; bi = t * PPT + i; }  // strict >: min idx
        }
        // wave argmax: f32 max reduce; ballot lowest lane among ties == min idx
        float m = bv;
#pragma unroll
        for (int d1 = 32; d1 >= 1; d1 >>= 1) m = fmaxf(m, __shfl_xor(m, d1, 64));
        u64 msk = __ballot(bv == m);
        int src = __ffsll((unsigned long long)msk) - 1;
        int biw = __shfl(bi, src, 64);
        if (lane == 0)
            cand[wave] = ((u64)__float_as_uint(m) << 32) |
                         (u64)(0xFFFFFFFFu - (u32)(base + biw));
        __syncthreads();
        if (wave == 0) {
            // stage-2: all lanes reduce the 16 wave candidates
            u64 c = cand[lane & 15];
#pragma unroll
            for (int d1 = 8; d1 >= 1; d1 >>= 1) {
                u64 o = __shfl_xor(c, d1, 64);
                c = (o > c) ? o : c;
            }
            // ---- writer: separate, loop-free, completes before polls ----
            const int g0 = (int)(0xFFFFFFFFu - (u32)(c & 0xFFFFFFFFull));
            float wx0 = 0.f, wy0 = 0.f, wz0 = 0.f;
            if (lane == 0) {
                const int lw = g0 - base;
                wx0 = P[lw * 3 + 0];
                wy0 = P[lw * 3 + 1];
                wz0 = P[lw * 3 + 2];
                int4v h0, h1;
                h0.x = s;                         // tag (both halves)
                h0.y = (int)(u32)(c >> 32);       // key hi = valbits
                h0.z = (int)(u32)c;               // key lo = ~idx
                h0.w = __float_as_int(wx0);
                h1.x = s;
                h1.y = __float_as_int(wy0);
                h1.z = __float_as_int(wz0);
                h1.w = 0;
                u32* sp = slot_b + ((size_t)s * BPB + j) * 8;
                asm volatile(
                    "global_store_dwordx4 %0, %2, off sc0 sc1\n\t"
                    "global_store_dwordx4 %1, %3, off sc0 sc1\n\t"
                    "global_store_dwordx4 %0, %2, off sc0\n\t"
                    "global_store_dwordx4 %1, %3, off sc0"
                    :: "v"(sp), "v"(sp + 4), "v"(h0), "v"(h1) : "memory");
            }
            // ---- pollers: fast bounded sc0 (local L2), then proven loop ----
            if (lane < BPB) {
                u64 k = c;                        // lane j keeps own candidate
                float wx = 0.f, wy = 0.f, wz = 0.f;
                if (lane != j) {
                    const u32* sp = slot_b + ((size_t)s * BPB + lane) * 8;
                    int4v a, bb;
                    int got = 0;
                    if (usefast) {
                        for (int it = 0; it < FAST_ATT && !got; ++it) {
                            asm volatile(
                                "global_load_dwordx4 %0, %2, off sc0\n\t"
                                "global_load_dwordx4 %1, %3, off sc0\n\t"
                                "s_waitcnt vmcnt(0)"
                                : "=&v"(a), "=&v"(bb)
                                : "v"(sp), "v"(sp + 4) : "memory");
                            got = (a.x == s && bb.x == s);
                        }
                        if (got) fastfail = 0;
                        else if (++fastfail >= DEMOTE_AFTER) usefast = 0;
                    }
                    if (!got) {
                        for (;;) {   // R7-proven terminating (sc0 sc1 world)
                            asm volatile(
                                "global_load_dwordx4 %0, %2, off sc0 sc1\n\t"
                                "global_load_dwordx4 %1, %3, off sc0 sc1\n\t"
                                "s_waitcnt vmcnt(0)"
                                : "=&v"(a), "=&v"(bb)
                                : "v"(sp), "v"(sp + 4) : "memory");
                            if (a.x == s && bb.x == s) break;
                        }
                    }
                    k = ((u64)(u32)a.y << 32) | (u32)a.z;
                    wx = __int_as_float(a.w);
                    wy = __int_as_float(bb.y);
                    wz = __int_as_float(bb.z);
                }
                // reduce over the 8 participants (lanes 0-7)
#pragma unroll
                for (int d1 = 4; d1 >= 1; d1 >>= 1) {
                    u64 o = __shfl_xor(k, d1, 64);
                    k = (o > k) ? o : k;
                }
                const int g = (int)(0xFFFFFFFFu - (u32)(k & 0xFFFFFFFFull));
                const int jw = (g >> 13) & 7;      // owning block (CHUNK=2^13)
                float sx = __shfl(wx, jw, 64);
                float sy = __shfl(wy, jw, 64);
                float sz = __shfl(wz, jw, 64);
                if (lane == 0) {
                    sel_hist[s] = g;
                    if (jw == j) { qsh[0] = wx0; qsh[1] = wy0; qsh[2] = wz0; }
                    else         { qsh[0] = sx;  qsh[1] = sy;  qsh[2] = sz;  }
                    if (j == 0) out_idx[s] = (float)g;
                }
            }
        }
        __syncthreads();
        qx = qsh[0]; qy = qsh[1]; qz = qsh[2];
    }

    if (j == 0) {
        const int gi = sel_hist[t];
        const float* __restrict__ p = pb + (size_t)gi * 3;
        out_pts[(size_t)t * 3 + 0] = p[0];
        out_pts[(size_t)t * 3 + 1] = p[1];
        out_pts[(size_t)t * 3 + 2] = p[2];
    }
}

// ---------------- R5 fallback: verified slot-store protocol (2 MB ws) -------
__global__ __launch_bounds__(NT) void fps_slots(const float* __restrict__ pts,
                                                float* __restrict__ out,
                                                u64* __restrict__ slots) {
#pragma clang fp contract(off)
    const int bid = blockIdx.x;
    const int b = bid >> 3;
    const int j = bid & 7;
    const int t = threadIdx.x;
    const int base = j * CHUNK;
    const float* __restrict__ pb = pts + (size_t)b * NP * 3;
    float* __restrict__ out_idx = out + (size_t)b * NS;
    float* __restrict__ out_pts = out + (size_t)NB * NS + (size_t)b * NS * 3;
    u64* __restrict__ slot_b = slots + (size_t)b * NS * BPB;

    __shared__ float P[CHUNK * 3];
    __shared__ u64 cand[NT / 64];
    __shared__ int sel_hist[NS];
    __shared__ float qsh[3];

    {
        const float4* __restrict__ src4 = (const float4*)(pb + (size_t)base * 3);
        float4* dst4 = (float4*)P;
#pragma unroll
        for (int k = 0; k < (CHUNK * 3 / 4) / NT; ++k) dst4[t + k * NT] = src4[t + k * NT];
    }
    float md[PPT];
#pragma unroll
    for (int i = 0; i < PPT; ++i) md[i] = 1e10f;
    if (t == 0) {
        sel_hist[0] = 0;
        if (j == 0) out_idx[0] = 0.0f;
        qsh[0] = pb[0]; qsh[1] = pb[1]; qsh[2] = pb[2];
    }
    __syncthreads();
    float qx = qsh[0], qy = qsh[1], qz = qsh[2];
    const int wave = t >> 6;
    const int lane = t & 63;
    for (int s = 1; s < NS; ++s) {
        float bestv = -1.0f;
        int besti = 0;
#pragma unroll
        for (int i = 0; i < PPT; ++i) {
            const int li = t + i * NT;
            const float* __restrict__ p = P + li * 3;
            float dx = p[0] - qx, dy = p[1] - qy, dz = p[2] - qz;
            float d = (dx * dx + dy * dy) + dz * dz;
            float nmd = fminf(md[i], d);
            md[i] = nmd;
            if (nmd > bestv) { bestv = nmd; besti = li; }
        }
        u64 pk = ((u64)__float_as_uint(bestv) << 32) |
                 (u64)(0xFFFFFFFFu - (u32)(base + besti));
#pragma unroll
        for (int m = 32; m >= 1; m >>= 1) {
            u64 o = __shfl_xor(pk, m, 64);
            pk = (o > pk) ? o : pk;
        }
        if (lane == 0) cand[wave] = pk;
        __syncthreads();
        if (wave == 0) {
            u64 c = (lane < 16) ? cand[lane] : 0ull;
#pragma unroll
            for (int m = 8; m >= 1; m >>= 1) {
                u64 o = __shfl_xor(c, m, 64);
                c = (o > c) ? o : c;
            }
            if (lane == 0) {
                __hip_atomic_store(&slot_b[(size_t)s * BPB + j], c,
                                   __ATOMIC_RELAXED, __HIP_MEMORY_SCOPE_AGENT);
            }
            u64 x = 0;
            if (lane < BPB) {
                const u64* sp = &slot_b[(size_t)s * BPB + lane];
                while ((x = __hip_atomic_load(sp, __ATOMIC_RELAXED,
                                              __HIP_MEMORY_SCOPE_AGENT)) == 0ull) {
                    __builtin_amdgcn_s_sleep(1);
                }
            }
#pragma unroll
            for (int m = 4; m >= 1; m >>= 1) {
                u64 o = __shfl_xor(x, m, 64);
                x = (o > x) ? o : x;
            }
            if (lane == 0) {
                int w = (int)(0xFFFFFFFFu - (u32)(x & 0xFFFFFFFFull));
                sel_hist[s] = w;
                const float* __restrict__ q = pb + (size_t)w * 3;
                qsh[0] = q[0]; qsh[1] = q[1]; qsh[2] = q[2];
                if (j == 0) out_idx[s] = (float)w;
            }
        }
        __syncthreads();
        qx = qsh[0]; qy = qsh[1]; qz = qsh[2];
    }
    if (j == 0) {
        const int gi = sel_hist[t];
        const float* __restrict__ p = pb + (size_t)gi * 3;
        out_pts[(size_t)t * 3 + 0] = p[0];
        out_pts[(size_t)t * 3 + 1] = p[1];
        out_pts[(size_t)t * 3 + 2] = p[2];
    }
}

extern "C" void kernel_launch(void* const* d_in, const int* in_sizes, int n_in,
                              void* d_out, int out_size, void* d_ws, size_t ws_size,
                              hipStream_t stream) {
    const float* pts = (const float*)d_in[0];
    float* out = (float*)d_out;
    (void)in_sizes; (void)n_in; (void)out_size;

    const size_t v11_bytes = (size_t)NB * NS * BPB * 32;            // 8 MB
    const size_t slot_bytes = (size_t)NB * NS * BPB * sizeof(u64);  // 2 MB
    if (ws_size >= v11_bytes) {
        u32* slots = (u32*)d_ws;
        hipMemsetAsync(d_ws, 0, v11_bytes, stream);
        void* args[] = {(void*)&pts, (void*)&out, (void*)&slots};
        hipLaunchCooperativeKernel((const void*)fps_v11, dim3(NB * BPB), dim3(NT),
                                   args, 0, stream);
    } else {
        u64* slots = (u64*)d_ws;
        hipMemsetAsync(d_ws, 0, slot_bytes, stream);
        void* args[] = {(void*)&pts, (void*)&out, (void*)&slots};
        hipLaunchCooperativeKernel((const void*)fps_slots, dim3(NB * BPB), dim3(NT),
                                   args, 0, stream);
    }
}

// Round 12
// 2602.550 us; speedup vs baseline: 1.3258x; 1.3258x over previous
//
#include <hip/hip_runtime.h>

#define NB 32
#define NP 65536
#define NS 1024
#define NT 1024

typedef unsigned long long u64;
typedef unsigned int u32;
typedef int int4v __attribute__((ext_vector_type(4)));

// ---------------- R12: parity-hot slots + BPB=16 ----------------------------
// Exchange slots: per batch, 2 parities x LBPB slots x 32B = 1KB (LBPB=16).
// Whole slot array = 32KB -> stays IF$/L2-hot; no cold HBM miss per poll
// (R7's per-s slots caused ~35MB of cold fetches = dominant exchange cost).
// Slot (b, par=s&1, j): h0={tag=s,keyhi,keylo,x}, h1={tag=s,y,z,0}; valid iff
// both tags==s (rejects memset-0 / 0xAA poison; cross-half skew). Parity-reuse
// safety: owner rewrites (par) only at s+2, reachable only after it saw OUR
// s+1 slot, which we write only after our s-poll finished (barrier-chained).
// Stale tag-matches across graph replays are bit-identical (determinism).
// CONTROL FLOW RULE (R8/R9 deadlock): writer store is a separate, loop-free
// `if (lane==0)` that COMPLETES before any poll loop starts.
// POLL RULE (R10/R11 lesson): polls MUST be sc0 sc1 (bypass L1+L2) — an sc0
// poll caches a clean stale line that remote writes never invalidate.
template <int LBPB>
__global__ __launch_bounds__(NT) void fps_par(const float* __restrict__ pts,
                                              float* __restrict__ out,
                                              u32* __restrict__ slots) {
#pragma clang fp contract(off)
    constexpr int CH = NP / LBPB;       // chunk per block
    constexpr int PP = CH / NT;         // points per thread
    constexpr int SH = (CH == 4096) ? 12 : 13;  // log2(CH)
    const int bid = blockIdx.x;
    const int b = bid / LBPB;           // batch: consecutive bids
    const int j = bid % LBPB;
    const int t = threadIdx.x;
    const int wave = t >> 6;
    const int lane = t & 63;
    const int base = j * CH;
    const float* __restrict__ pb = pts + (size_t)b * NP * 3;
    float* __restrict__ out_idx = out + (size_t)b * NS;
    float* __restrict__ out_pts = out + (size_t)NB * NS + (size_t)b * NS * 3;
    u32* __restrict__ slot_b = slots + (size_t)b * 2 * LBPB * 8;  // u32 words

    __shared__ float P[CH * 3];
    __shared__ u64 cand[NT / 64];
    __shared__ int sel_hist[NS];
    __shared__ float qsh[3];

    // stage chunk into LDS, coalesced float4
    {
        const float4* __restrict__ src4 = (const float4*)(pb + (size_t)base * 3);
        float4* dst4 = (float4*)P;
#pragma unroll
        for (int k = 0; k < (CH * 3 / 4) / NT; ++k) dst4[t + k * NT] = src4[t + k * NT];
    }
    if (t == 0) {
        sel_hist[0] = 0;
        if (j == 0) out_idx[0] = 0.0f;
        qsh[0] = pb[0]; qsh[1] = pb[1]; qsh[2] = pb[2];   // first sel = point 0
    }
    __syncthreads();

    // points -> registers, CONSECUTIVE range [t*PP, t*PP+PP):
    // lowest lane == lowest global idx (exact ballot tie-break, verified R10/11)
    float px[PP], py[PP], pz[PP], md[PP];
#pragma unroll
    for (int i = 0; i < PP; ++i) {
        const int li = t * PP + i;
        px[i] = P[li * 3 + 0];
        py[i] = P[li * 3 + 1];
        pz[i] = P[li * 3 + 2];
        md[i] = 1e10f;
    }
    float qx = qsh[0], qy = qsh[1], qz = qsh[2];

    for (int s = 1; s < NS; ++s) {
        float bv = -1.0f;
        int bi = 0;
#pragma unroll
        for (int i = 0; i < PP; ++i) {
            float dx = px[i] - qx;
            float dy = py[i] - qy;
            float dz = pz[i] - qz;
            float d = (dx * dx + dy * dy) + dz * dz;   // match np reduce order
            float nmd = fminf(md[i], d);
            md[i] = nmd;
            if (nmd > bv) { bv = nmd; bi = t * PP + i; }   // strict >: min idx
        }
        // wave argmax: f32 max reduce; ballot lowest lane among ties == min idx
        float m = bv;
#pragma unroll
        for (int d1 = 32; d1 >= 1; d1 >>= 1) m = fmaxf(m, __shfl_xor(m, d1, 64));
        u64 msk = __ballot(bv == m);
        int src = __ffsll((unsigned long long)msk) - 1;
        int biw = __shfl(bi, src, 64);
        if (lane == 0)
            cand[wave] = ((u64)__float_as_uint(m) << 32) |
                         (u64)(0xFFFFFFFFu - (u32)(base + biw));
        __syncthreads();
        if (wave == 0) {
            // stage-2: reduce the 16 wave candidates (all lanes)
            u64 c = cand[lane & 15];
#pragma unroll
            for (int d1 = 8; d1 >= 1; d1 >>= 1) {
                u64 o = __shfl_xor(c, d1, 64);
                c = (o > c) ? o : c;
            }
            const int par = s & 1;
            // ---- writer: separate, loop-free, completes before polls ----
            const int g0 = (int)(0xFFFFFFFFu - (u32)(c & 0xFFFFFFFFull));
            float wx0 = 0.f, wy0 = 0.f, wz0 = 0.f;
            if (lane == 0) {
                const int lw = g0 - base;
                wx0 = P[lw * 3 + 0];
                wy0 = P[lw * 3 + 1];
                wz0 = P[lw * 3 + 2];
                int4v h0, h1;
                h0.x = s;                         // tag (both halves)
                h0.y = (int)(u32)(c >> 32);       // key hi = valbits
                h0.z = (int)(u32)c;               // key lo = ~idx
                h0.w = __float_as_int(wx0);
                h1.x = s;
                h1.y = __float_as_int(wy0);
                h1.z = __float_as_int(wz0);
                h1.w = 0;
                u32* sp = slot_b + ((size_t)par * LBPB + j) * 8;
                asm volatile(
                    "global_store_dwordx4 %0, %2, off sc0 sc1\n\t"
                    "global_store_dwordx4 %1, %3, off sc0 sc1"
                    :: "v"(sp), "v"(sp + 4), "v"(h0), "v"(h1) : "memory");
            }
            // ---- pollers: sc0 sc1 only (bypass L1+L2; R10/R11 lesson) ----
            if (lane < LBPB) {
                u64 k = c;                        // lane j keeps own candidate
                float wx = 0.f, wy = 0.f, wz = 0.f;
                if (lane != j) {
                    const u32* sp = slot_b + ((size_t)par * LBPB + lane) * 8;
                    int4v a, bb;
                    for (;;) {
                        asm volatile(
                            "global_load_dwordx4 %0, %2, off sc0 sc1\n\t"
                            "global_load_dwordx4 %1, %3, off sc0 sc1\n\t"
                            "s_waitcnt vmcnt(0)"
                            : "=&v"(a), "=&v"(bb)
                            : "v"(sp), "v"(sp + 4) : "memory");
                        if (a.x == s && bb.x == s) break;
                    }
                    k = ((u64)(u32)a.y << 32) | (u32)a.z;
                    wx = __int_as_float(a.w);
                    wy = __int_as_float(bb.y);
                    wz = __int_as_float(bb.z);
                }
                // reduce over the LBPB participants
#pragma unroll
                for (int d1 = LBPB / 2; d1 >= 1; d1 >>= 1) {
                    u64 o = __shfl_xor(k, d1, 64);
                    k = (o > k) ? o : k;
                }
                const int g = (int)(0xFFFFFFFFu - (u32)(k & 0xFFFFFFFFull));
                const int jw = (g >> SH) & (LBPB - 1);   // owning block
                float sx = __shfl(wx, jw, 64);
                float sy = __shfl(wy, jw, 64);
                float sz = __shfl(wz, jw, 64);
                if (lane == 0) {
                    sel_hist[s] = g;
                    if (jw == j) { qsh[0] = wx0; qsh[1] = wy0; qsh[2] = wz0; }
                    else         { qsh[0] = sx;  qsh[1] = sy;  qsh[2] = sz;  }
                    if (j == 0) out_idx[s] = (float)g;
                }
            }
        }
        __syncthreads();
        qx = qsh[0]; qy = qsh[1]; qz = qsh[2];
    }

    if (j == 0) {
        const int gi = sel_hist[t];
        const float* __restrict__ p = pb + (size_t)gi * 3;
        out_pts[(size_t)t * 3 + 0] = p[0];
        out_pts[(size_t)t * 3 + 1] = p[1];
        out_pts[(size_t)t * 3 + 2] = p[2];
    }
}

// ---------------- R7-verbatim fallback (per-s 8MB slots, proven 2.22ms) -----
#define BPB 8
#define CHUNK (NP / BPB)
#define PPT (CHUNK / NT)
__global__ __launch_bounds__(NT) void fps_v7(const float* __restrict__ pts,
                                             float* __restrict__ out,
                                             u32* __restrict__ slots) {
#pragma clang fp contract(off)
    const int bid = blockIdx.x;
    const int b = bid >> 3;
    const int j = bid & 7;
    const int t = threadIdx.x;
    const int base = j * CHUNK;
    const float* __restrict__ pb = pts + (size_t)b * NP * 3;
    float* __restrict__ out_idx = out + (size_t)b * NS;
    float* __restrict__ out_pts = out + (size_t)NB * NS + (size_t)b * NS * 3;
    u32* __restrict__ slot_b = slots + (size_t)b * NS * BPB * 8;

    __shared__ float P[CHUNK * 3];
    __shared__ u64 cand[NT / 64];
    __shared__ int sel_hist[NS];
    __shared__ float qsh[3];

    {
        const float4* __restrict__ src4 = (const float4*)(pb + (size_t)base * 3);
        float4* dst4 = (float4*)P;
#pragma unroll
        for (int k = 0; k < (CHUNK * 3 / 4) / NT; ++k) dst4[t + k * NT] = src4[t + k * NT];
    }
    if (t == 0) {
        sel_hist[0] = 0;
        if (j == 0) out_idx[0] = 0.0f;
        qsh[0] = pb[0]; qsh[1] = pb[1]; qsh[2] = pb[2];
    }
    __syncthreads();
    float px[PPT], py[PPT], pz[PPT], md[PPT];
#pragma unroll
    for (int i = 0; i < PPT; ++i) {
        const int li = t + i * NT;
        px[i] = P[li * 3 + 0];
        py[i] = P[li * 3 + 1];
        pz[i] = P[li * 3 + 2];
        md[i] = 1e10f;
    }
    float qx = qsh[0], qy = qsh[1], qz = qsh[2];
    const int wave = t >> 6;
    const int lane = t & 63;
    for (int s = 1; s < NS; ++s) {
        float bestv = -1.0f;
        int besti = 0;
#pragma unroll
        for (int i = 0; i < PPT; ++i) {
            float dx = px[i] - qx, dy = py[i] - qy, dz = pz[i] - qz;
            float d = (dx * dx + dy * dy) + dz * dz;
            float nmd = fminf(md[i], d);
            md[i] = nmd;
            if (nmd > bestv) { bestv = nmd; besti = t + i * NT; }
        }
        u64 pk = ((u64)__float_as_uint(bestv) << 32) |
                 (u64)(0xFFFFFFFFu - (u32)(base + besti));
#pragma unroll
        for (int m = 32; m >= 1; m >>= 1) {
            u64 o = __shfl_xor(pk, m, 64);
            pk = (o > pk) ? o : pk;
        }
        if (lane == 0) cand[wave] = pk;
        __syncthreads();
        if (wave == 0) {
            u64 c = cand[lane & 15];
#pragma unroll
            for (int m = 8; m >= 1; m >>= 1) {
                u64 o = __shfl_xor(c, m, 64);
                c = (o > c) ? o : c;
            }
            const int g0 = (int)(0xFFFFFFFFu - (u32)(c & 0xFFFFFFFFull));
            float wx0 = 0.f, wy0 = 0.f, wz0 = 0.f;
            if (lane == 0) {
                const int lw = g0 - base;
                wx0 = P[lw * 3 + 0];
                wy0 = P[lw * 3 + 1];
                wz0 = P[lw * 3 + 2];
                int4v h0, h1;
                h0.x = (int)(u32)(c & 0xFFFFFFFFull);
                h0.y = (int)(u32)(c >> 32);
                h0.z = __float_as_int(wx0);
                h0.w = __float_as_int(wy0);
                h1.x = h0.x;
                h1.y = h0.y;
                h1.z = __float_as_int(wz0);
                h1.w = 0;
                u32* sp = slot_b + ((size_t)s * BPB + j) * 8;
                asm volatile(
                    "global_store_dwordx4 %0, %2, off sc0 sc1\n\t"
                    "global_store_dwordx4 %1, %3, off sc0 sc1"
                    :: "v"(sp), "v"(sp + 4), "v"(h0), "v"(h1) : "memory");
            }
            if (lane < BPB) {
                u64 k = c;
                float wx = 0.f, wy = 0.f, wz = 0.f;
                if (lane != j) {
                    const u32* sp = slot_b + ((size_t)s * BPB + lane) * 8;
                    int4v a, bb;
                    for (;;) {
                        asm volatile(
                            "global_load_dwordx4 %0, %2, off sc0 sc1\n\t"
                            "global_load_dwordx4 %1, %3, off sc0 sc1\n\t"
                            "s_waitcnt vmcnt(0)"
                            : "=&v"(a), "=&v"(bb)
                            : "v"(sp), "v"(sp + 4) : "memory");
                        if (a.x != 0 && a.x == bb.x && a.y == bb.y) break;
                    }
                    k = ((u64)(u32)a.y << 32) | (u32)a.x;
                    wx = __int_as_float(a.z);
                    wy = __int_as_float(a.w);
                    wz = __int_as_float(bb.z);
                }
#pragma unroll
                for (int d1 = 4; d1 >= 1; d1 >>= 1) {
                    u64 o = __shfl_xor(k, d1, 64);
                    k = (o > k) ? o : k;
                }
                const int g = (int)(0xFFFFFFFFu - (u32)(k & 0xFFFFFFFFull));
                const int jw = (g >> 13) & 7;
                float sx = __shfl(wx, jw, 64);
                float sy = __shfl(wy, jw, 64);
                float sz = __shfl(wz, jw, 64);
                if (lane == 0) {
                    sel_hist[s] = g;
                    if (jw == j) { qsh[0] = wx0; qsh[1] = wy0; qsh[2] = wz0; }
                    else         { qsh[0] = sx;  qsh[1] = sy;  qsh[2] = sz;  }
                    if (j == 0) out_idx[s] = (float)g;
                }
            }
        }
        __syncthreads();
        qx = qsh[0]; qy = qsh[1]; qz = qsh[2];
    }
    if (j == 0) {
        const int gi = sel_hist[t];
        const float* __restrict__ p = pb + (size_t)gi * 3;
        out_pts[(size_t)t * 3 + 0] = p[0];
        out_pts[(size_t)t * 3 + 1] = p[1];
        out_pts[(size_t)t * 3 + 2] = p[2];
    }
}

extern "C" void kernel_launch(void* const* d_in, const int* in_sizes, int n_in,
                              void* d_out, int out_size, void* d_ws, size_t ws_size,
                              hipStream_t stream) {
    const float* pts = (const float*)d_in[0];
    float* out = (float*)d_out;
    (void)in_sizes; (void)n_in; (void)out_size;

    const size_t v7_bytes = (size_t)NB * NS * BPB * 32;   // 8 MB (fallback)
    if (ws_size >= v7_bytes) {
        u32* slots = (u32*)d_ws;
        hipMemsetAsync(d_ws, 0, v7_bytes, stream);        // covers both layouts
        void* args[] = {(void*)&pts, (void*)&out, (void*)&slots};
        hipError_t e = hipLaunchCooperativeKernel((const void*)fps_par<16>,
                                                  dim3(NB * 16), dim3(NT),
                                                  args, 0, stream);
        if (e != hipSuccess) {
            hipLaunchCooperativeKernel((const void*)fps_v7, dim3(NB * BPB),
                                       dim3(NT), args, 0, stream);
        }
    } else {
        // minimal fallback: parity slots need only 32 KB
        u32* slots = (u32*)d_ws;
        hipMemsetAsync(d_ws, 0, (size_t)NB * 2 * 16 * 32, stream);
        void* args[] = {(void*)&pts, (void*)&out, (void*)&slots};
        hipLaunchCooperativeKernel((const void*)fps_par<16>, dim3(NB * 16),
                                   dim3(NT), args, 0, stream);
    }
}